// Round 15
// baseline (196.366 us; speedup 1.0000x reference)
//
#include <hip/hip_runtime.h>

#define N_NODES 10000
#define N_EDGES 320000
#define BCAP    96      // bucket capacity per (gso,col); deg ~ Poisson(32), +11 sigma
// Backward-functional formulation, gather propagation over single-pass
// fixed-capacity column buckets (no prefix/scatter):
//   bucket[(e,c)] holds packed (bf16(v)<<16 | row) for all edges (r,c,v) of gso e
//   w_out[c] = sum_p w_in[row_p] * v_p         (no atomics in stages)
// Vectors (A = S0, B = S1, right-multiplication of row functionals):
//   wA  [n]: {a1=e0A, a2=e0A^2, b1=e0B, b2=e0B^2}
//   wB0 [n]: {c1=a2A, d1=b1A, e1=b2A, -}       (stage2 via buckets e=0)
//   wB1 [n]: {f1=b2B, g1=a1B, h1=a2B, -}       (stage2 via buckets e=1)
//   wC0 [n]: {c1A, d1A, e1A, -}                (stage3 via buckets e=0)
//   wC1 [n]: {f1B, g1B, h1B, -}                (stage3 via buckets e=1)
// U[k][256] = sum_n w_k[n] * x[b][n][f], two-phase (plain partials + reduce —
// device-scope atomics into U measured at ~24/cy device-wide = 45 us wall).

__device__ __forceinline__ unsigned short f2bf(float x) {
    unsigned int u = __float_as_uint(x);
    unsigned int r = (u + 0x7fff + ((u >> 16) & 1)) >> 16;   // RNE
    return (unsigned short)r;
}
__device__ __forceinline__ float bfhi(unsigned int u) { return __uint_as_float(u & 0xffff0000u); }

// ---------------------------------------------------------------- pass 1: bucket build + stage0
__global__ void bucket_kernel(const int* __restrict__ ei, const float* __restrict__ ev,
                              int* __restrict__ cnt, unsigned int* __restrict__ bkt,
                              float* __restrict__ wA) {
    int j = blockIdx.x * 256 + threadIdx.x;       // 2500*256 = 640000 exactly
    int e = j / N_EDGES, t = j - e * N_EDGES;
    int r = ei[e * 2 * N_EDGES + t];
    int c = ei[e * 2 * N_EDGES + N_EDGES + t];
    float v = ev[e * N_EDGES + t];
    int pos = atomicAdd(&cnt[e * N_NODES + c], 1);
    if (pos < BCAP)
        bkt[(e * N_NODES + c) * BCAP + pos] = ((unsigned int)f2bf(v) << 16) | (unsigned int)r;
    if (r == 0)   // a1[c] += v (gso0) / b1[c] += v (gso1)
        atomicAdd(&wA[c * 4 + (e ? 2 : 0)], v);
}

// ---------------------------------------------------------------- stage 1: a2 = a1*A, b2 = b1*B
// 16-lane unit per (gso, col); gather over bucket; one coalesced store.
__global__ __launch_bounds__(256) void gstage1_kernel(
        const unsigned int* __restrict__ bkt, const int* __restrict__ cnt,
        float* __restrict__ wA) {
    int t = threadIdx.x;
    int gu = (blockIdx.x << 4) + (t >> 4);
    int li = t & 15;
    int e = (gu >= N_NODES) ? 1 : 0;
    int c = gu - e * N_NODES;
    int nc = cnt[e * N_NODES + c]; if (nc > BCAP) nc = BCAP;
    const unsigned int* bp = bkt + (e * N_NODES + c) * BCAP;
    int koff = e ? 2 : 0;
    float acc = 0.f;
    for (int p = li; p < nc; p += 16) {
        unsigned int u = bp[p];
        acc += bfhi(u) * wA[(u & 0xffff) * 4 + koff];   // reads .x/.z only, writes .y/.w
    }
    acc += __shfl_xor(acc, 1); acc += __shfl_xor(acc, 2);
    acc += __shfl_xor(acc, 4); acc += __shfl_xor(acc, 8);
    if (li == 0) wA[c * 4 + koff + 1] = acc;
}

// ---------------------------------------------------------------- stage 2: {c1,d1,e1} / {f1,g1,h1}
__global__ __launch_bounds__(256) void gstage2_kernel(
        const unsigned int* __restrict__ bkt, const int* __restrict__ cnt,
        const float* __restrict__ wA, float4* __restrict__ wB0, float4* __restrict__ wB1) {
    int t = threadIdx.x;
    int gu = (blockIdx.x << 4) + (t >> 4);
    int li = t & 15;
    int e = (gu >= N_NODES) ? 1 : 0;
    int c = gu - e * N_NODES;
    int nc = cnt[e * N_NODES + c]; if (nc > BCAP) nc = BCAP;
    const unsigned int* bp = bkt + (e * N_NODES + c) * BCAP;
    const float4* wAp = (const float4*)wA;
    float x0 = 0.f, x1 = 0.f, x2 = 0.f;
    for (int p = li; p < nc; p += 16) {
        unsigned int u = bp[p];
        float v = bfhi(u);
        float4 wr = wAp[u & 0xffff];
        if (e == 0) { x0 += wr.y * v; x1 += wr.z * v; x2 += wr.w * v; }  // c1=a2A, d1=b1A, e1=b2A
        else        { x0 += wr.w * v; x1 += wr.x * v; x2 += wr.y * v; }  // f1=b2B, g1=a1B, h1=a2B
    }
    x0 += __shfl_xor(x0, 1); x0 += __shfl_xor(x0, 2); x0 += __shfl_xor(x0, 4); x0 += __shfl_xor(x0, 8);
    x1 += __shfl_xor(x1, 1); x1 += __shfl_xor(x1, 2); x1 += __shfl_xor(x1, 4); x1 += __shfl_xor(x1, 8);
    x2 += __shfl_xor(x2, 1); x2 += __shfl_xor(x2, 2); x2 += __shfl_xor(x2, 4); x2 += __shfl_xor(x2, 8);
    if (li == 0) {
        float4 o = make_float4(x0, x1, x2, 0.f);
        if (e == 0) wB0[c] = o; else wB1[c] = o;
    }
}

// ---------------------------------------------------------------- stage 3: {c1A,d1A,e1A} / {f1B,g1B,h1B}
__global__ __launch_bounds__(256) void gstage3_kernel(
        const unsigned int* __restrict__ bkt, const int* __restrict__ cnt,
        const float4* __restrict__ wB0, const float4* __restrict__ wB1,
        float4* __restrict__ wC0, float4* __restrict__ wC1) {
    int t = threadIdx.x;
    int gu = (blockIdx.x << 4) + (t >> 4);
    int li = t & 15;
    int e = (gu >= N_NODES) ? 1 : 0;
    int c = gu - e * N_NODES;
    int nc = cnt[e * N_NODES + c]; if (nc > BCAP) nc = BCAP;
    const unsigned int* bp = bkt + (e * N_NODES + c) * BCAP;
    const float4* win = e ? wB1 : wB0;
    float x0 = 0.f, x1 = 0.f, x2 = 0.f;
    for (int p = li; p < nc; p += 16) {
        unsigned int u = bp[p];
        float v = bfhi(u);
        float4 wr = win[u & 0xffff];
        x0 += wr.x * v; x1 += wr.y * v; x2 += wr.z * v;
    }
    x0 += __shfl_xor(x0, 1); x0 += __shfl_xor(x0, 2); x0 += __shfl_xor(x0, 4); x0 += __shfl_xor(x0, 8);
    x1 += __shfl_xor(x1, 1); x1 += __shfl_xor(x1, 2); x1 += __shfl_xor(x1, 4); x1 += __shfl_xor(x1, 8);
    x2 += __shfl_xor(x2, 1); x2 += __shfl_xor(x2, 2); x2 += __shfl_xor(x2, 4); x2 += __shfl_xor(x2, 8);
    if (li == 0) {
        float4 o = make_float4(x0, x1, x2, 0.f);
        if (e == 0) wC0[c] = o; else wC1[c] = o;
    }
}

// ---------------------------------------------------------------- U phase A: per-block partials
// 625 blocks x 256 thr; block = 16 consecutive nodes, fully unrolled; partials
// written with plain coalesced stores (no atomics). S sums stay atomic (4/block).
__global__ __launch_bounds__(256) void ugemm_kernel(const float* __restrict__ x,
                                                    const float* __restrict__ wA,
                                                    const float4* __restrict__ wB0,
                                                    const float4* __restrict__ wB1,
                                                    const float4* __restrict__ wC0,
                                                    const float4* __restrict__ wC1,
                                                    float* __restrict__ Upart,
                                                    float* __restrict__ S) {
    int t = threadIdx.x;
    int b = t >> 6, f = t & 63;
    int n0 = blockIdx.x * 16;                     // 625*16 = 10000 exactly
    const float* xp = x + b * (N_NODES * 64) + f;
    const float4* wAp = (const float4*)wA;
    float acc[16];
    #pragma unroll
    for (int k = 0; k < 16; ++k) acc[k] = 0.f;
    float s0 = 0.f, s1 = 0.f, s2 = 0.f, s3 = 0.f;
    #pragma unroll
    for (int j = 0; j < 16; ++j) {
        int n = n0 + j;
        float4 a  = wAp[n];
        float4 p0 = wB0[n], p1 = wB1[n];
        float4 q0 = wC0[n], q1 = wC1[n];
        float xv = xp[n * 64];
        acc[0]  += a.x * xv;  acc[1]  += a.y * xv;
        acc[2]  += a.z * xv;  acc[3]  += a.w * xv;
        acc[4]  += p0.x * xv; acc[5]  += p0.y * xv; acc[6]  += p0.z * xv;
        acc[7]  += p1.x * xv; acc[8]  += p1.y * xv; acc[9]  += p1.z * xv;
        acc[10] += q0.x * xv; acc[11] += q0.y * xv; acc[12] += q0.z * xv;
        acc[13] += q1.x * xv; acc[14] += q1.y * xv; acc[15] += q1.z * xv;
        if (t == 0) { s0 += a.x; s1 += a.y; s2 += a.z; s3 += a.w; }
    }
    float* up = Upart + blockIdx.x * 4096;
    #pragma unroll
    for (int k = 0; k < 16; ++k)
        up[k * 256 + t] = acc[k];
    if (t == 0) {
        atomicAdd(&S[0], s0); atomicAdd(&S[1], s1);
        atomicAdd(&S[2], s2); atomicAdd(&S[3], s3);
    }
}

// ---------------------------------------------------------------- U phase B: reduce 625 partials
// 128 blocks x 256 thr; output o = blk*32 + (t>>3); 8 lanes sum ~78 strided
// partials each (independent loads, pipelined), shfl-combine, plain store.
__global__ __launch_bounds__(256) void ureduce_kernel(const float* __restrict__ Upart,
                                                      float* __restrict__ U) {
    int t = threadIdx.x;
    int o = blockIdx.x * 32 + (t >> 3);
    int lane = t & 7;
    float acc = 0.f;
    for (int p = lane; p < 625; p += 8)
        acc += Upart[p * 4096 + o];
    acc += __shfl_xor(acc, 1);
    acc += __shfl_xor(acc, 2);
    acc += __shfl_xor(acc, 4);
    if (lane == 0) U[o] = acc;
}

// ---------------------------------------------------------------- final stage 1
// block = (s,g), 25 blocks x 512 thr. W1c_s (32 KB) in LDS; src = U[k] (or x
// node 0). Block 0 zeroes out[512].
// U k-slots: 0-3 a1,a2,b1,b2; 4-6 c1,d1,e1; 7-9 f1,g1,h1; 10-12 c1A,d1A,e1A; 13-15 f1B,g1B,h1B.
__global__ __launch_bounds__(512) void final_T_kernel(
        const float* __restrict__ x, const float* __restrict__ U,
        const float* __restrict__ S,
        const float* __restrict__ W1, const float* __restrict__ b1,
        float* __restrict__ T, float* __restrict__ out) {
    __shared__ float Ws[8192];     // 32 KB: W1c_s[f0][f1]
    __shared__ float src[256];
    int blk = blockIdx.x;
    int s = blk / 5, g = blk - s * 5;
    int t = threadIdx.x;
    if (blk == 0) out[t] = 0.f;
    const int w1off[5] = { 0, 8192, 16384, 32768, 40960 };
    const float4* wsrc = (const float4*)(W1 + w1off[s]);
    const float4* wsrc0 = (const float4*)(W1 + 24576);     // W1[1,0], added when s==0
    float4* wdst = (float4*)Ws;
    #pragma unroll
    for (int i = 0; i < 4; ++i) {
        float4 v = wsrc[i * 512 + t];
        if (s == 0) {
            float4 v2 = wsrc0[i * 512 + t];
            v.x += v2.x; v.y += v2.y; v.z += v2.z; v.w += v2.w;
        }
        wdst[i * 512 + t] = v;
    }
    if (t < 256) {
        const int hmap[5] = { -1, 0, 1, 2, 3 };   // z_s[0]: x0, a1, a2, b1, b2
        const int umap[4][5] = {
            { 0, 1, 4,  8, 14 },   // ek0=a1: a1, a2, c1,  g1,  g1B
            { 1, 4, 10, 9, 15 },   // ek1=a2: a2, c1, c1A, h1,  h1B
            { 2, 5, 11, 3,  7 },   // ek2=b1: b1, d1, d1A, b2,  f1
            { 3, 6, 12, 7, 13 },   // ek3=b2: b2, e1, e1A, f1,  f1B
        };
        int k = (g == 0) ? hmap[s] : umap[g - 1][s];
        float sv;
        if (k < 0) sv = x[(t >> 6) * (N_NODES * 64) + (t & 63)];  // x[b][0][f]
        else       sv = U[k * 256 + t];
        src[t] = sv;
    }
    __syncthreads();
    int b = t >> 7, f1 = t & 127;
    const float* sp = src + b * 64;
    float acc = 0.f;
    #pragma unroll 16
    for (int f0 = 0; f0 < 64; ++f0)
        acc += sp[f0] * Ws[f0 * 128 + f1];
    if (s == 0) acc += (g == 0) ? b1[f1] : S[g - 1] * b1[f1];
    atomicAdd(&T[g * 512 + t], acc);
}

// ---------------------------------------------------------------- final stage 2
__global__ __launch_bounds__(512) void final_out_kernel(
        const float* __restrict__ T, const float* __restrict__ W2,
        const float* __restrict__ b2, float* __restrict__ out) {
    __shared__ float Ws[16384];    // 64 KB: W2c_g[f1][f2]
    __shared__ float Ts[512];
    int g = blockIdx.x;
    int t = threadIdx.x;
    const int w2off[5] = { 0, 16384, 32768, 65536, 81920 };  // W2[00],[01],[02],[11],[12]
    const float4* wsrc = (const float4*)(W2 + w2off[g]);
    const float4* wsrc0 = (const float4*)(W2 + 49152);       // W2[1,0], added when g==0
    float4* wdst = (float4*)Ws;
    #pragma unroll
    for (int i = 0; i < 8; ++i) {
        float4 v = wsrc[i * 512 + t];
        if (g == 0) {
            float4 v2 = wsrc0[i * 512 + t];
            v.x += v2.x; v.y += v2.y; v.z += v2.z; v.w += v2.w;
        }
        wdst[i * 512 + t] = v;
    }
    Ts[t] = T[g * 512 + t];
    __syncthreads();
    int b = t >> 7, f2 = t & 127;
    const float* tp = Ts + b * 128;
    float acc = (g == 0) ? b2[f2] : 0.f;
    #pragma unroll 16
    for (int f1 = 0; f1 < 128; ++f1)
        acc += tp[f1] * Ws[f1 * 128 + f2];
    atomicAdd(&out[t], acc);
}

// ----------------------------------------------------------------
extern "C" void kernel_launch(void* const* d_in, const int* in_sizes, int n_in,
                              void* d_out, int out_size, void* d_ws, size_t ws_size,
                              hipStream_t stream) {
    const float* x  = (const float*)d_in[0];
    const int*   ei = (const int*)d_in[1];
    const float* ev = (const float*)d_in[2];
    const float* W1 = (const float*)d_in[3];
    const float* b1 = (const float*)d_in[4];
    const float* W2 = (const float*)d_in[5];
    const float* b2 = (const float*)d_in[6];
    float* out = (float*)d_out;

    char* ws = (char*)d_ws;
    size_t off = 0;
    auto alloc = [&](size_t bytes) { size_t o = off; off += (bytes + 255) & ~(size_t)255; return o; };
    size_t o_bkt   = alloc((size_t)2 * N_NODES * BCAP * 4);   // 7.7 MB buckets (cnt-bounded)
    size_t o_upart = alloc((size_t)625 * 4096 * 4);           // 10.24 MB partials (fully written)
    size_t o_U     = alloc((size_t)16 * 256 * 4);             // reduced U (assigned by ureduce)
    size_t o_zero  = off;                                     // zeroed region starts here
    size_t o_cnt   = alloc((size_t)2 * N_NODES * 4);
    size_t o_wA    = alloc((size_t)N_NODES * 4 * 4);          // {a1,a2,b1,b2}
    size_t o_wB0   = alloc((size_t)N_NODES * 4 * 4);          // {c1,d1,e1,-}
    size_t o_wB1   = alloc((size_t)N_NODES * 4 * 4);          // {f1,g1,h1,-}
    size_t o_wC0   = alloc((size_t)N_NODES * 4 * 4);          // {c1A,d1A,e1A,-}
    size_t o_wC1   = alloc((size_t)N_NODES * 4 * 4);          // {f1B,g1B,h1B,-}
    size_t o_S     = alloc(4 * 4);
    size_t o_T     = alloc((size_t)5 * 512 * 4);
    size_t zero_bytes = off - o_zero;

    unsigned int* bkt = (unsigned int*)(ws + o_bkt);
    float*  Upart = (float*)(ws + o_upart);
    float*  U     = (float*)(ws + o_U);
    int*    cnt   = (int*)(ws + o_cnt);
    float*  wA    = (float*)(ws + o_wA);
    float4* wB0   = (float4*)(ws + o_wB0);
    float4* wB1   = (float4*)(ws + o_wB1);
    float4* wC0   = (float4*)(ws + o_wC0);
    float4* wC1   = (float4*)(ws + o_wC1);
    float*  S     = (float*)(ws + o_S);
    float*  T     = (float*)(ws + o_T);

    hipMemsetAsync(ws + o_zero, 0, zero_bytes, stream);

    bucket_kernel  <<<2500, 256, 0, stream>>>(ei, ev, cnt, bkt, wA);
    gstage1_kernel <<<1250, 256, 0, stream>>>(bkt, cnt, wA);
    gstage2_kernel <<<1250, 256, 0, stream>>>(bkt, cnt, wA, wB0, wB1);
    gstage3_kernel <<<1250, 256, 0, stream>>>(bkt, cnt, wB0, wB1, wC0, wC1);
    ugemm_kernel   <<<625,  256, 0, stream>>>(x, wA, wB0, wB1, wC0, wC1, Upart, S);
    ureduce_kernel <<<128,  256, 0, stream>>>(Upart, U);
    final_T_kernel <<<25,   512, 0, stream>>>(x, U, S, W1, b1, T, out);
    final_out_kernel<<<5,   512, 0, stream>>>(T, W2, b2, out);
}

// Round 16
// 177.762 us; speedup vs baseline: 1.1047x; 1.1047x over previous
//
#include <hip/hip_runtime.h>

#define N_NODES 10000
#define N_EDGES 320000
#define BCAP    96      // bucket capacity per (gso,col); deg ~ Poisson(32), +11 sigma
// Backward-functional formulation, gather propagation over single-pass
// fixed-capacity column buckets (no prefix/scatter):
//   bucket[(e,c)] holds packed (bf16(v)<<16 | row) for all edges (r,c,v) of gso e
//   w_out[c] = sum_p w_in[row_p] * v_p         (no atomics in stages)
// Vectors (A = S0, B = S1, right-multiplication of row functionals):
//   wA  [n]: {a1=e0A, a2=e0A^2, b1=e0B, b2=e0B^2}
//   wB0 [n]: {c1=a2A, d1=b1A, e1=b2A, -}       (stage2 via buckets e=0)
//   wB1 [n]: {f1=b2B, g1=a1B, h1=a2B, -}       (stage2 via buckets e=1)
//   wC0 [n]: {c1A, d1A, e1A, -}                (stage3 via buckets e=0)
//   wC1 [n]: {f1B, g1B, h1B, -}                (stage3 via buckets e=1)
// U[k][256] = sum_n w_k[n] * x[b][n][f]; 64 blocks x 16-node unrolled batches
// -> 262k atomics (~4.5 us at measured ~24 atomics/cy) with 16-way load MLP.

__device__ __forceinline__ unsigned short f2bf(float x) {
    unsigned int u = __float_as_uint(x);
    unsigned int r = (u + 0x7fff + ((u >> 16) & 1)) >> 16;   // RNE
    return (unsigned short)r;
}
__device__ __forceinline__ float bfhi(unsigned int u) { return __uint_as_float(u & 0xffff0000u); }

// ---------------------------------------------------------------- pass 1: bucket build + stage0
__global__ void bucket_kernel(const int* __restrict__ ei, const float* __restrict__ ev,
                              int* __restrict__ cnt, unsigned int* __restrict__ bkt,
                              float* __restrict__ wA) {
    int j = blockIdx.x * 256 + threadIdx.x;       // 2500*256 = 640000 exactly
    int e = j / N_EDGES, t = j - e * N_EDGES;
    int r = ei[e * 2 * N_EDGES + t];
    int c = ei[e * 2 * N_EDGES + N_EDGES + t];
    float v = ev[e * N_EDGES + t];
    int pos = atomicAdd(&cnt[e * N_NODES + c], 1);
    if (pos < BCAP)
        bkt[(e * N_NODES + c) * BCAP + pos] = ((unsigned int)f2bf(v) << 16) | (unsigned int)r;
    if (r == 0)   // a1[c] += v (gso0) / b1[c] += v (gso1)
        atomicAdd(&wA[c * 4 + (e ? 2 : 0)], v);
}

// ---------------------------------------------------------------- stage 1: a2 = a1*A, b2 = b1*B
// 16-lane unit per (gso, col); gather over bucket; one coalesced store.
__global__ __launch_bounds__(256) void gstage1_kernel(
        const unsigned int* __restrict__ bkt, const int* __restrict__ cnt,
        float* __restrict__ wA) {
    int t = threadIdx.x;
    int gu = (blockIdx.x << 4) + (t >> 4);
    int li = t & 15;
    int e = (gu >= N_NODES) ? 1 : 0;
    int c = gu - e * N_NODES;
    int nc = cnt[e * N_NODES + c]; if (nc > BCAP) nc = BCAP;
    const unsigned int* bp = bkt + (e * N_NODES + c) * BCAP;
    int koff = e ? 2 : 0;
    float acc = 0.f;
    for (int p = li; p < nc; p += 16) {
        unsigned int u = bp[p];
        acc += bfhi(u) * wA[(u & 0xffff) * 4 + koff];   // reads .x/.z only, writes .y/.w
    }
    acc += __shfl_xor(acc, 1); acc += __shfl_xor(acc, 2);
    acc += __shfl_xor(acc, 4); acc += __shfl_xor(acc, 8);
    if (li == 0) wA[c * 4 + koff + 1] = acc;
}

// ---------------------------------------------------------------- stage 2: {c1,d1,e1} / {f1,g1,h1}
__global__ __launch_bounds__(256) void gstage2_kernel(
        const unsigned int* __restrict__ bkt, const int* __restrict__ cnt,
        const float* __restrict__ wA, float4* __restrict__ wB0, float4* __restrict__ wB1) {
    int t = threadIdx.x;
    int gu = (blockIdx.x << 4) + (t >> 4);
    int li = t & 15;
    int e = (gu >= N_NODES) ? 1 : 0;
    int c = gu - e * N_NODES;
    int nc = cnt[e * N_NODES + c]; if (nc > BCAP) nc = BCAP;
    const unsigned int* bp = bkt + (e * N_NODES + c) * BCAP;
    const float4* wAp = (const float4*)wA;
    float x0 = 0.f, x1 = 0.f, x2 = 0.f;
    for (int p = li; p < nc; p += 16) {
        unsigned int u = bp[p];
        float v = bfhi(u);
        float4 wr = wAp[u & 0xffff];
        if (e == 0) { x0 += wr.y * v; x1 += wr.z * v; x2 += wr.w * v; }  // c1=a2A, d1=b1A, e1=b2A
        else        { x0 += wr.w * v; x1 += wr.x * v; x2 += wr.y * v; }  // f1=b2B, g1=a1B, h1=a2B
    }
    x0 += __shfl_xor(x0, 1); x0 += __shfl_xor(x0, 2); x0 += __shfl_xor(x0, 4); x0 += __shfl_xor(x0, 8);
    x1 += __shfl_xor(x1, 1); x1 += __shfl_xor(x1, 2); x1 += __shfl_xor(x1, 4); x1 += __shfl_xor(x1, 8);
    x2 += __shfl_xor(x2, 1); x2 += __shfl_xor(x2, 2); x2 += __shfl_xor(x2, 4); x2 += __shfl_xor(x2, 8);
    if (li == 0) {
        float4 o = make_float4(x0, x1, x2, 0.f);
        if (e == 0) wB0[c] = o; else wB1[c] = o;
    }
}

// ---------------------------------------------------------------- stage 3: {c1A,d1A,e1A} / {f1B,g1B,h1B}
__global__ __launch_bounds__(256) void gstage3_kernel(
        const unsigned int* __restrict__ bkt, const int* __restrict__ cnt,
        const float4* __restrict__ wB0, const float4* __restrict__ wB1,
        float4* __restrict__ wC0, float4* __restrict__ wC1) {
    int t = threadIdx.x;
    int gu = (blockIdx.x << 4) + (t >> 4);
    int li = t & 15;
    int e = (gu >= N_NODES) ? 1 : 0;
    int c = gu - e * N_NODES;
    int nc = cnt[e * N_NODES + c]; if (nc > BCAP) nc = BCAP;
    const unsigned int* bp = bkt + (e * N_NODES + c) * BCAP;
    const float4* win = e ? wB1 : wB0;
    float x0 = 0.f, x1 = 0.f, x2 = 0.f;
    for (int p = li; p < nc; p += 16) {
        unsigned int u = bp[p];
        float v = bfhi(u);
        float4 wr = win[u & 0xffff];
        x0 += wr.x * v; x1 += wr.y * v; x2 += wr.z * v;
    }
    x0 += __shfl_xor(x0, 1); x0 += __shfl_xor(x0, 2); x0 += __shfl_xor(x0, 4); x0 += __shfl_xor(x0, 8);
    x1 += __shfl_xor(x1, 1); x1 += __shfl_xor(x1, 2); x1 += __shfl_xor(x1, 4); x1 += __shfl_xor(x1, 8);
    x2 += __shfl_xor(x2, 1); x2 += __shfl_xor(x2, 2); x2 += __shfl_xor(x2, 4); x2 += __shfl_xor(x2, 8);
    if (li == 0) {
        float4 o = make_float4(x0, x1, x2, 0.f);
        if (e == 0) wC0[c] = o; else wC1[c] = o;
    }
}

// ---------------------------------------------------------------- U accumulation + base sums
// 64 blocks x 256 thr; grid-strided 16-node batches, fully unrolled (16
// independent coalesced x loads in flight per batch; w loads block-uniform).
// 16 atomicAdds/thread TOTAL (64x256x16 = 262k atomics ~ 4.5 us).
__global__ __launch_bounds__(256) void ugemm_kernel(const float* __restrict__ x,
                                                    const float* __restrict__ wA,
                                                    const float4* __restrict__ wB0,
                                                    const float4* __restrict__ wB1,
                                                    const float4* __restrict__ wC0,
                                                    const float4* __restrict__ wC1,
                                                    float* __restrict__ U,
                                                    float* __restrict__ S) {
    int t = threadIdx.x;
    int b = t >> 6, f = t & 63;
    const float* xp = x + b * (N_NODES * 64) + f;
    const float4* wAp = (const float4*)wA;
    float acc[16];
    #pragma unroll
    for (int k = 0; k < 16; ++k) acc[k] = 0.f;
    float s0 = 0.f, s1 = 0.f, s2 = 0.f, s3 = 0.f;
    for (int m = blockIdx.x; m < 625; m += 64) {      // 625 batches of 16 nodes
        int n0 = m * 16;
        #pragma unroll
        for (int j = 0; j < 16; ++j) {
            int n = n0 + j;
            float4 a  = wAp[n];
            float4 p0 = wB0[n], p1 = wB1[n];
            float4 q0 = wC0[n], q1 = wC1[n];
            float xv = xp[n * 64];
            acc[0]  += a.x * xv;  acc[1]  += a.y * xv;
            acc[2]  += a.z * xv;  acc[3]  += a.w * xv;
            acc[4]  += p0.x * xv; acc[5]  += p0.y * xv; acc[6]  += p0.z * xv;
            acc[7]  += p1.x * xv; acc[8]  += p1.y * xv; acc[9]  += p1.z * xv;
            acc[10] += q0.x * xv; acc[11] += q0.y * xv; acc[12] += q0.z * xv;
            acc[13] += q1.x * xv; acc[14] += q1.y * xv; acc[15] += q1.z * xv;
            if (t == 0) { s0 += a.x; s1 += a.y; s2 += a.z; s3 += a.w; }
        }
    }
    #pragma unroll
    for (int k = 0; k < 16; ++k)
        atomicAdd(&U[k * 256 + t], acc[k]);
    if (t == 0) {
        atomicAdd(&S[0], s0); atomicAdd(&S[1], s1);
        atomicAdd(&S[2], s2); atomicAdd(&S[3], s3);
    }
}

// ---------------------------------------------------------------- final stage 1
// block = (s,g), 25 blocks x 512 thr. W1c_s (32 KB) in LDS; src = U[k] (or x
// node 0). Block 0 zeroes out[512].
// U k-slots: 0-3 a1,a2,b1,b2; 4-6 c1,d1,e1; 7-9 f1,g1,h1; 10-12 c1A,d1A,e1A; 13-15 f1B,g1B,h1B.
__global__ __launch_bounds__(512) void final_T_kernel(
        const float* __restrict__ x, const float* __restrict__ U,
        const float* __restrict__ S,
        const float* __restrict__ W1, const float* __restrict__ b1,
        float* __restrict__ T, float* __restrict__ out) {
    __shared__ float Ws[8192];     // 32 KB: W1c_s[f0][f1]
    __shared__ float src[256];
    int blk = blockIdx.x;
    int s = blk / 5, g = blk - s * 5;
    int t = threadIdx.x;
    if (blk == 0) out[t] = 0.f;
    const int w1off[5] = { 0, 8192, 16384, 32768, 40960 };
    const float4* wsrc = (const float4*)(W1 + w1off[s]);
    const float4* wsrc0 = (const float4*)(W1 + 24576);     // W1[1,0], added when s==0
    float4* wdst = (float4*)Ws;
    #pragma unroll
    for (int i = 0; i < 4; ++i) {
        float4 v = wsrc[i * 512 + t];
        if (s == 0) {
            float4 v2 = wsrc0[i * 512 + t];
            v.x += v2.x; v.y += v2.y; v.z += v2.z; v.w += v2.w;
        }
        wdst[i * 512 + t] = v;
    }
    if (t < 256) {
        const int hmap[5] = { -1, 0, 1, 2, 3 };   // z_s[0]: x0, a1, a2, b1, b2
        const int umap[4][5] = {
            { 0, 1, 4,  8, 14 },   // ek0=a1: a1, a2, c1,  g1,  g1B
            { 1, 4, 10, 9, 15 },   // ek1=a2: a2, c1, c1A, h1,  h1B
            { 2, 5, 11, 3,  7 },   // ek2=b1: b1, d1, d1A, b2,  f1
            { 3, 6, 12, 7, 13 },   // ek3=b2: b2, e1, e1A, f1,  f1B
        };
        int k = (g == 0) ? hmap[s] : umap[g - 1][s];
        float sv;
        if (k < 0) sv = x[(t >> 6) * (N_NODES * 64) + (t & 63)];  // x[b][0][f]
        else       sv = U[k * 256 + t];
        src[t] = sv;
    }
    __syncthreads();
    int b = t >> 7, f1 = t & 127;
    const float* sp = src + b * 64;
    float acc = 0.f;
    #pragma unroll 16
    for (int f0 = 0; f0 < 64; ++f0)
        acc += sp[f0] * Ws[f0 * 128 + f1];
    if (s == 0) acc += (g == 0) ? b1[f1] : S[g - 1] * b1[f1];
    atomicAdd(&T[g * 512 + t], acc);
}

// ---------------------------------------------------------------- final stage 2
__global__ __launch_bounds__(512) void final_out_kernel(
        const float* __restrict__ T, const float* __restrict__ W2,
        const float* __restrict__ b2, float* __restrict__ out) {
    __shared__ float Ws[16384];    // 64 KB: W2c_g[f1][f2]
    __shared__ float Ts[512];
    int g = blockIdx.x;
    int t = threadIdx.x;
    const int w2off[5] = { 0, 16384, 32768, 65536, 81920 };  // W2[00],[01],[02],[11],[12]
    const float4* wsrc = (const float4*)(W2 + w2off[g]);
    const float4* wsrc0 = (const float4*)(W2 + 49152);       // W2[1,0], added when g==0
    float4* wdst = (float4*)Ws;
    #pragma unroll
    for (int i = 0; i < 8; ++i) {
        float4 v = wsrc[i * 512 + t];
        if (g == 0) {
            float4 v2 = wsrc0[i * 512 + t];
            v.x += v2.x; v.y += v2.y; v.z += v2.z; v.w += v2.w;
        }
        wdst[i * 512 + t] = v;
    }
    Ts[t] = T[g * 512 + t];
    __syncthreads();
    int b = t >> 7, f2 = t & 127;
    const float* tp = Ts + b * 128;
    float acc = (g == 0) ? b2[f2] : 0.f;
    #pragma unroll 16
    for (int f1 = 0; f1 < 128; ++f1)
        acc += tp[f1] * Ws[f1 * 128 + f2];
    atomicAdd(&out[t], acc);
}

// ----------------------------------------------------------------
extern "C" void kernel_launch(void* const* d_in, const int* in_sizes, int n_in,
                              void* d_out, int out_size, void* d_ws, size_t ws_size,
                              hipStream_t stream) {
    const float* x  = (const float*)d_in[0];
    const int*   ei = (const int*)d_in[1];
    const float* ev = (const float*)d_in[2];
    const float* W1 = (const float*)d_in[3];
    const float* b1 = (const float*)d_in[4];
    const float* W2 = (const float*)d_in[5];
    const float* b2 = (const float*)d_in[6];
    float* out = (float*)d_out;

    char* ws = (char*)d_ws;
    size_t off = 0;
    auto alloc = [&](size_t bytes) { size_t o = off; off += (bytes + 255) & ~(size_t)255; return o; };
    size_t o_bkt   = alloc((size_t)2 * N_NODES * BCAP * 4);   // 7.7 MB buckets (cnt-bounded)
    size_t o_zero  = off;                                     // zeroed region starts here
    size_t o_cnt   = alloc((size_t)2 * N_NODES * 4);
    size_t o_wA    = alloc((size_t)N_NODES * 4 * 4);          // {a1,a2,b1,b2}
    size_t o_wB0   = alloc((size_t)N_NODES * 4 * 4);          // {c1,d1,e1,-}
    size_t o_wB1   = alloc((size_t)N_NODES * 4 * 4);          // {f1,g1,h1,-}
    size_t o_wC0   = alloc((size_t)N_NODES * 4 * 4);          // {c1A,d1A,e1A,-}
    size_t o_wC1   = alloc((size_t)N_NODES * 4 * 4);          // {f1B,g1B,h1B,-}
    size_t o_U     = alloc((size_t)16 * 256 * 4);             // U (atomic-accumulated)
    size_t o_S     = alloc(4 * 4);
    size_t o_T     = alloc((size_t)5 * 512 * 4);
    size_t zero_bytes = off - o_zero;

    unsigned int* bkt = (unsigned int*)(ws + o_bkt);
    int*    cnt   = (int*)(ws + o_cnt);
    float*  wA    = (float*)(ws + o_wA);
    float4* wB0   = (float4*)(ws + o_wB0);
    float4* wB1   = (float4*)(ws + o_wB1);
    float4* wC0   = (float4*)(ws + o_wC0);
    float4* wC1   = (float4*)(ws + o_wC1);
    float*  U     = (float*)(ws + o_U);
    float*  S     = (float*)(ws + o_S);
    float*  T     = (float*)(ws + o_T);

    hipMemsetAsync(ws + o_zero, 0, zero_bytes, stream);

    bucket_kernel  <<<2500, 256, 0, stream>>>(ei, ev, cnt, bkt, wA);
    gstage1_kernel <<<1250, 256, 0, stream>>>(bkt, cnt, wA);
    gstage2_kernel <<<1250, 256, 0, stream>>>(bkt, cnt, wA, wB0, wB1);
    gstage3_kernel <<<1250, 256, 0, stream>>>(bkt, cnt, wB0, wB1, wC0, wC1);
    ugemm_kernel   <<<64,   256, 0, stream>>>(x, wA, wB0, wB1, wC0, wC1, U, S);
    final_T_kernel <<<25,   512, 0, stream>>>(x, U, S, W1, b1, T, out);
    final_out_kernel<<<5,   512, 0, stream>>>(T, W2, b2, out);
}

// Round 17
// 163.427 us; speedup vs baseline: 1.2015x; 1.0877x over previous
//
#include <hip/hip_runtime.h>

#define N_NODES 10000
#define N_EDGES 320000
#define BCAP    96      // bucket capacity per (gso,col); deg ~ Poisson(32), +11 sigma
#define NCPY    8       // U/S accumulation copies (contention 625 -> ~78 per address)
// Backward-functional formulation, gather propagation over single-pass
// fixed-capacity column buckets (no prefix/scatter):
//   bucket[(e,c)] holds packed (bf16(v)<<16 | row) for all edges (r,c,v) of gso e
//   w_out[c] = sum_p w_in[row_p] * v_p         (no atomics in stages)
// Vectors (A = S0, B = S1, right-multiplication of row functionals):
//   wA  [n]: {a1=e0A, a2=e0A^2, b1=e0B, b2=e0B^2}
//   wB0 [n]: {c1=a2A, d1=b1A, e1=b2A, -}       (stage2 via buckets e=0)
//   wB1 [n]: {f1=b2B, g1=a1B, h1=a2B, -}       (stage2 via buckets e=1)
//   wC0 [n]: {c1A, d1A, e1A, -}                (stage3 via buckets e=0)
//   wC1 [n]: {f1B, g1B, h1B, -}                (stage3 via buckets e=1)
// U[k][256] = sum_n w_k[n] * x[b][n][f]; 625 blocks x 16-node unrolled batch
// (full parallelism) atomically accumulating into 8 spread copies.

__device__ __forceinline__ unsigned short f2bf(float x) {
    unsigned int u = __float_as_uint(x);
    unsigned int r = (u + 0x7fff + ((u >> 16) & 1)) >> 16;   // RNE
    return (unsigned short)r;
}
__device__ __forceinline__ float bfhi(unsigned int u) { return __uint_as_float(u & 0xffff0000u); }

// ---------------------------------------------------------------- pass 1: bucket build + stage0
__global__ void bucket_kernel(const int* __restrict__ ei, const float* __restrict__ ev,
                              int* __restrict__ cnt, unsigned int* __restrict__ bkt,
                              float* __restrict__ wA) {
    int j = blockIdx.x * 256 + threadIdx.x;       // 2500*256 = 640000 exactly
    int e = j / N_EDGES, t = j - e * N_EDGES;
    int r = ei[e * 2 * N_EDGES + t];
    int c = ei[e * 2 * N_EDGES + N_EDGES + t];
    float v = ev[e * N_EDGES + t];
    int pos = atomicAdd(&cnt[e * N_NODES + c], 1);
    if (pos < BCAP)
        bkt[(e * N_NODES + c) * BCAP + pos] = ((unsigned int)f2bf(v) << 16) | (unsigned int)r;
    if (r == 0)   // a1[c] += v (gso0) / b1[c] += v (gso1)
        atomicAdd(&wA[c * 4 + (e ? 2 : 0)], v);
}

// ---------------------------------------------------------------- stage 1: a2 = a1*A, b2 = b1*B
// 16-lane unit per (gso, col); gather over bucket; one coalesced store.
__global__ __launch_bounds__(256) void gstage1_kernel(
        const unsigned int* __restrict__ bkt, const int* __restrict__ cnt,
        float* __restrict__ wA) {
    int t = threadIdx.x;
    int gu = (blockIdx.x << 4) + (t >> 4);
    int li = t & 15;
    int e = (gu >= N_NODES) ? 1 : 0;
    int c = gu - e * N_NODES;
    int nc = cnt[e * N_NODES + c]; if (nc > BCAP) nc = BCAP;
    const unsigned int* bp = bkt + (e * N_NODES + c) * BCAP;
    int koff = e ? 2 : 0;
    float acc = 0.f;
    for (int p = li; p < nc; p += 16) {
        unsigned int u = bp[p];
        acc += bfhi(u) * wA[(u & 0xffff) * 4 + koff];   // reads .x/.z only, writes .y/.w
    }
    acc += __shfl_xor(acc, 1); acc += __shfl_xor(acc, 2);
    acc += __shfl_xor(acc, 4); acc += __shfl_xor(acc, 8);
    if (li == 0) wA[c * 4 + koff + 1] = acc;
}

// ---------------------------------------------------------------- stage 2: {c1,d1,e1} / {f1,g1,h1}
__global__ __launch_bounds__(256) void gstage2_kernel(
        const unsigned int* __restrict__ bkt, const int* __restrict__ cnt,
        const float* __restrict__ wA, float4* __restrict__ wB0, float4* __restrict__ wB1) {
    int t = threadIdx.x;
    int gu = (blockIdx.x << 4) + (t >> 4);
    int li = t & 15;
    int e = (gu >= N_NODES) ? 1 : 0;
    int c = gu - e * N_NODES;
    int nc = cnt[e * N_NODES + c]; if (nc > BCAP) nc = BCAP;
    const unsigned int* bp = bkt + (e * N_NODES + c) * BCAP;
    const float4* wAp = (const float4*)wA;
    float x0 = 0.f, x1 = 0.f, x2 = 0.f;
    for (int p = li; p < nc; p += 16) {
        unsigned int u = bp[p];
        float v = bfhi(u);
        float4 wr = wAp[u & 0xffff];
        if (e == 0) { x0 += wr.y * v; x1 += wr.z * v; x2 += wr.w * v; }  // c1=a2A, d1=b1A, e1=b2A
        else        { x0 += wr.w * v; x1 += wr.x * v; x2 += wr.y * v; }  // f1=b2B, g1=a1B, h1=a2B
    }
    x0 += __shfl_xor(x0, 1); x0 += __shfl_xor(x0, 2); x0 += __shfl_xor(x0, 4); x0 += __shfl_xor(x0, 8);
    x1 += __shfl_xor(x1, 1); x1 += __shfl_xor(x1, 2); x1 += __shfl_xor(x1, 4); x1 += __shfl_xor(x1, 8);
    x2 += __shfl_xor(x2, 1); x2 += __shfl_xor(x2, 2); x2 += __shfl_xor(x2, 4); x2 += __shfl_xor(x2, 8);
    if (li == 0) {
        float4 o = make_float4(x0, x1, x2, 0.f);
        if (e == 0) wB0[c] = o; else wB1[c] = o;
    }
}

// ---------------------------------------------------------------- stage 3: {c1A,d1A,e1A} / {f1B,g1B,h1B}
__global__ __launch_bounds__(256) void gstage3_kernel(
        const unsigned int* __restrict__ bkt, const int* __restrict__ cnt,
        const float4* __restrict__ wB0, const float4* __restrict__ wB1,
        float4* __restrict__ wC0, float4* __restrict__ wC1) {
    int t = threadIdx.x;
    int gu = (blockIdx.x << 4) + (t >> 4);
    int li = t & 15;
    int e = (gu >= N_NODES) ? 1 : 0;
    int c = gu - e * N_NODES;
    int nc = cnt[e * N_NODES + c]; if (nc > BCAP) nc = BCAP;
    const unsigned int* bp = bkt + (e * N_NODES + c) * BCAP;
    const float4* win = e ? wB1 : wB0;
    float x0 = 0.f, x1 = 0.f, x2 = 0.f;
    for (int p = li; p < nc; p += 16) {
        unsigned int u = bp[p];
        float v = bfhi(u);
        float4 wr = win[u & 0xffff];
        x0 += wr.x * v; x1 += wr.y * v; x2 += wr.z * v;
    }
    x0 += __shfl_xor(x0, 1); x0 += __shfl_xor(x0, 2); x0 += __shfl_xor(x0, 4); x0 += __shfl_xor(x0, 8);
    x1 += __shfl_xor(x1, 1); x1 += __shfl_xor(x1, 2); x1 += __shfl_xor(x1, 4); x1 += __shfl_xor(x1, 8);
    x2 += __shfl_xor(x2, 1); x2 += __shfl_xor(x2, 2); x2 += __shfl_xor(x2, 4); x2 += __shfl_xor(x2, 8);
    if (li == 0) {
        float4 o = make_float4(x0, x1, x2, 0.f);
        if (e == 0) wC0[c] = o; else wC1[c] = o;
    }
}

// ---------------------------------------------------------------- U accumulation + base sums
// 625 blocks x 256 thr; block = 16 consecutive nodes, fully unrolled (16
// independent coalesced x loads in flight). Atomic accumulation spread over
// NCPY copies of U/S (contention per address 625 -> ~78).
__global__ __launch_bounds__(256) void ugemm_kernel(const float* __restrict__ x,
                                                    const float* __restrict__ wA,
                                                    const float4* __restrict__ wB0,
                                                    const float4* __restrict__ wB1,
                                                    const float4* __restrict__ wC0,
                                                    const float4* __restrict__ wC1,
                                                    float* __restrict__ U8,
                                                    float* __restrict__ S8) {
    int t = threadIdx.x;
    int b = t >> 6, f = t & 63;
    int n0 = blockIdx.x * 16;                     // 625*16 = 10000 exactly
    int cp = blockIdx.x & (NCPY - 1);
    const float* xp = x + b * (N_NODES * 64) + f;
    const float4* wAp = (const float4*)wA;
    float acc[16];
    #pragma unroll
    for (int k = 0; k < 16; ++k) acc[k] = 0.f;
    float s0 = 0.f, s1 = 0.f, s2 = 0.f, s3 = 0.f;
    #pragma unroll
    for (int j = 0; j < 16; ++j) {
        int n = n0 + j;
        float4 a  = wAp[n];
        float4 p0 = wB0[n], p1 = wB1[n];
        float4 q0 = wC0[n], q1 = wC1[n];
        float xv = xp[n * 64];
        acc[0]  += a.x * xv;  acc[1]  += a.y * xv;
        acc[2]  += a.z * xv;  acc[3]  += a.w * xv;
        acc[4]  += p0.x * xv; acc[5]  += p0.y * xv; acc[6]  += p0.z * xv;
        acc[7]  += p1.x * xv; acc[8]  += p1.y * xv; acc[9]  += p1.z * xv;
        acc[10] += q0.x * xv; acc[11] += q0.y * xv; acc[12] += q0.z * xv;
        acc[13] += q1.x * xv; acc[14] += q1.y * xv; acc[15] += q1.z * xv;
        if (t == 0) { s0 += a.x; s1 += a.y; s2 += a.z; s3 += a.w; }
    }
    float* up = U8 + cp * 4096;
    #pragma unroll
    for (int k = 0; k < 16; ++k)
        atomicAdd(&up[k * 256 + t], acc[k]);
    if (t == 0) {
        float* sp = S8 + cp * 4;
        atomicAdd(&sp[0], s0); atomicAdd(&sp[1], s1);
        atomicAdd(&sp[2], s2); atomicAdd(&sp[3], s3);
    }
}

// ---------------------------------------------------------------- final stage 1
// block = (s,g), 25 blocks x 512 thr. W1c_s (32 KB) in LDS; src = U[k] (folded
// over the NCPY copies) or x node 0. Block 0 zeroes out[512].
// U k-slots: 0-3 a1,a2,b1,b2; 4-6 c1,d1,e1; 7-9 f1,g1,h1; 10-12 c1A,d1A,e1A; 13-15 f1B,g1B,h1B.
__global__ __launch_bounds__(512) void final_T_kernel(
        const float* __restrict__ x, const float* __restrict__ U8,
        const float* __restrict__ S8,
        const float* __restrict__ W1, const float* __restrict__ b1,
        float* __restrict__ T, float* __restrict__ out) {
    __shared__ float Ws[8192];     // 32 KB: W1c_s[f0][f1]
    __shared__ float src[256];
    int blk = blockIdx.x;
    int s = blk / 5, g = blk - s * 5;
    int t = threadIdx.x;
    if (blk == 0) out[t] = 0.f;
    const int w1off[5] = { 0, 8192, 16384, 32768, 40960 };
    const float4* wsrc = (const float4*)(W1 + w1off[s]);
    const float4* wsrc0 = (const float4*)(W1 + 24576);     // W1[1,0], added when s==0
    float4* wdst = (float4*)Ws;
    #pragma unroll
    for (int i = 0; i < 4; ++i) {
        float4 v = wsrc[i * 512 + t];
        if (s == 0) {
            float4 v2 = wsrc0[i * 512 + t];
            v.x += v2.x; v.y += v2.y; v.z += v2.z; v.w += v2.w;
        }
        wdst[i * 512 + t] = v;
    }
    if (t < 256) {
        const int hmap[5] = { -1, 0, 1, 2, 3 };   // z_s[0]: x0, a1, a2, b1, b2
        const int umap[4][5] = {
            { 0, 1, 4,  8, 14 },   // ek0=a1: a1, a2, c1,  g1,  g1B
            { 1, 4, 10, 9, 15 },   // ek1=a2: a2, c1, c1A, h1,  h1B
            { 2, 5, 11, 3,  7 },   // ek2=b1: b1, d1, d1A, b2,  f1
            { 3, 6, 12, 7, 13 },   // ek3=b2: b2, e1, e1A, f1,  f1B
        };
        int k = (g == 0) ? hmap[s] : umap[g - 1][s];
        float sv;
        if (k < 0) {
            sv = x[(t >> 6) * (N_NODES * 64) + (t & 63)];  // x[b][0][f]
        } else {
            sv = 0.f;
            #pragma unroll
            for (int c = 0; c < NCPY; ++c) sv += U8[c * 4096 + k * 256 + t];
        }
        src[t] = sv;
    }
    __syncthreads();
    int b = t >> 7, f1 = t & 127;
    const float* sp = src + b * 64;
    float acc = 0.f;
    #pragma unroll 16
    for (int f0 = 0; f0 < 64; ++f0)
        acc += sp[f0] * Ws[f0 * 128 + f1];
    if (s == 0) {
        if (g == 0) acc += b1[f1];
        else {
            float Sg = 0.f;
            #pragma unroll
            for (int c = 0; c < NCPY; ++c) Sg += S8[c * 4 + (g - 1)];
            acc += Sg * b1[f1];
        }
    }
    atomicAdd(&T[g * 512 + t], acc);
}

// ---------------------------------------------------------------- final stage 2
__global__ __launch_bounds__(512) void final_out_kernel(
        const float* __restrict__ T, const float* __restrict__ W2,
        const float* __restrict__ b2, float* __restrict__ out) {
    __shared__ float Ws[16384];    // 64 KB: W2c_g[f1][f2]
    __shared__ float Ts[512];
    int g = blockIdx.x;
    int t = threadIdx.x;
    const int w2off[5] = { 0, 16384, 32768, 65536, 81920 };  // W2[00],[01],[02],[11],[12]
    const float4* wsrc = (const float4*)(W2 + w2off[g]);
    const float4* wsrc0 = (const float4*)(W2 + 49152);       // W2[1,0], added when g==0
    float4* wdst = (float4*)Ws;
    #pragma unroll
    for (int i = 0; i < 8; ++i) {
        float4 v = wsrc[i * 512 + t];
        if (g == 0) {
            float4 v2 = wsrc0[i * 512 + t];
            v.x += v2.x; v.y += v2.y; v.z += v2.z; v.w += v2.w;
        }
        wdst[i * 512 + t] = v;
    }
    Ts[t] = T[g * 512 + t];
    __syncthreads();
    int b = t >> 7, f2 = t & 127;
    const float* tp = Ts + b * 128;
    float acc = (g == 0) ? b2[f2] : 0.f;
    #pragma unroll 16
    for (int f1 = 0; f1 < 128; ++f1)
        acc += tp[f1] * Ws[f1 * 128 + f2];
    atomicAdd(&out[t], acc);
}

// ----------------------------------------------------------------
extern "C" void kernel_launch(void* const* d_in, const int* in_sizes, int n_in,
                              void* d_out, int out_size, void* d_ws, size_t ws_size,
                              hipStream_t stream) {
    const float* x  = (const float*)d_in[0];
    const int*   ei = (const int*)d_in[1];
    const float* ev = (const float*)d_in[2];
    const float* W1 = (const float*)d_in[3];
    const float* b1 = (const float*)d_in[4];
    const float* W2 = (const float*)d_in[5];
    const float* b2 = (const float*)d_in[6];
    float* out = (float*)d_out;

    char* ws = (char*)d_ws;
    size_t off = 0;
    auto alloc = [&](size_t bytes) { size_t o = off; off += (bytes + 255) & ~(size_t)255; return o; };
    size_t o_bkt   = alloc((size_t)2 * N_NODES * BCAP * 4);   // 7.7 MB buckets (cnt-bounded)
    size_t o_zero  = off;                                     // zeroed region starts here
    size_t o_cnt   = alloc((size_t)2 * N_NODES * 4);
    size_t o_wA    = alloc((size_t)N_NODES * 4 * 4);          // {a1,a2,b1,b2}
    size_t o_wB0   = alloc((size_t)N_NODES * 4 * 4);          // {c1,d1,e1,-}
    size_t o_wB1   = alloc((size_t)N_NODES * 4 * 4);          // {f1,g1,h1,-}
    size_t o_wC0   = alloc((size_t)N_NODES * 4 * 4);          // {c1A,d1A,e1A,-}
    size_t o_wC1   = alloc((size_t)N_NODES * 4 * 4);          // {f1B,g1B,h1B,-}
    size_t o_U     = alloc((size_t)NCPY * 16 * 256 * 4);      // U copies (atomic-accumulated)
    size_t o_S     = alloc((size_t)NCPY * 4 * 4);
    size_t o_T     = alloc((size_t)5 * 512 * 4);
    size_t zero_bytes = off - o_zero;

    unsigned int* bkt = (unsigned int*)(ws + o_bkt);
    int*    cnt   = (int*)(ws + o_cnt);
    float*  wA    = (float*)(ws + o_wA);
    float4* wB0   = (float4*)(ws + o_wB0);
    float4* wB1   = (float4*)(ws + o_wB1);
    float4* wC0   = (float4*)(ws + o_wC0);
    float4* wC1   = (float4*)(ws + o_wC1);
    float*  U8    = (float*)(ws + o_U);
    float*  S8    = (float*)(ws + o_S);
    float*  T     = (float*)(ws + o_T);

    hipMemsetAsync(ws + o_zero, 0, zero_bytes, stream);

    bucket_kernel  <<<2500, 256, 0, stream>>>(ei, ev, cnt, bkt, wA);
    gstage1_kernel <<<1250, 256, 0, stream>>>(bkt, cnt, wA);
    gstage2_kernel <<<1250, 256, 0, stream>>>(bkt, cnt, wA, wB0, wB1);
    gstage3_kernel <<<1250, 256, 0, stream>>>(bkt, cnt, wB0, wB1, wC0, wC1);
    ugemm_kernel   <<<625,  256, 0, stream>>>(x, wA, wB0, wB1, wC0, wC1, U8, S8);
    final_T_kernel <<<25,   512, 0, stream>>>(x, U8, S8, W1, b1, T, out);
    final_out_kernel<<<5,   512, 0, stream>>>(T, W2, b2, out);
}